// Round 1
// 777.138 us; speedup vs baseline: 1.1866x; 1.1866x over previous
//
#include <hip/hip_runtime.h>

#define N0v 614400
#define N1v 40960
#define BATCHv 4096

typedef __attribute__((ext_vector_type(8))) short short8;
typedef __attribute__((ext_vector_type(4))) float floatx4;

static __device__ __forceinline__ float flog1p(float v) { return __logf(v + 1.0f); }
static __device__ __forceinline__ float sigf(float v) { return 1.0f / (1.0f + __expf(-v)); }
static __device__ __forceinline__ float tanhfast(float v) {
    return 1.0f - 2.0f / (__expf(2.0f * v) + 1.0f);
}
static __device__ __forceinline__ unsigned short f2bf(float f) {
    union { float f; unsigned u; } v; v.f = f;
    unsigned r = v.u + 0x7FFFu + ((v.u >> 16) & 1u);   // RNE
    return (unsigned short)(r >> 16);
}
static __device__ __forceinline__ float bf2f(unsigned short u) {
    return __uint_as_float(((unsigned)u) << 16);
}

// ---------------------------------------------------------------------------
// Weight pre-convert: fp32 -> bf16 copies in ws, plus bsum = b_ih + b_hh.
// Sizes: Wp 128x128=16384; Ws0/Wn0 256x128=32768; Wih/Whh 1024x256=262144;
// bsum 1024. Total 607232 elements -> grid 2372 x 256.
// ---------------------------------------------------------------------------
__global__ __launch_bounds__(256) void cvt_weights_kernel(
    const float* __restrict__ Wp, const float* __restrict__ Ws0,
    const float* __restrict__ Wn0, const float* __restrict__ Wih,
    const float* __restrict__ Whh, const float* __restrict__ bih,
    const float* __restrict__ bhh,
    unsigned short* __restrict__ Wpb, unsigned short* __restrict__ Ws0b,
    unsigned short* __restrict__ Wn0b, unsigned short* __restrict__ Wihb,
    unsigned short* __restrict__ Whhb, float* __restrict__ bsum)
{
    const int g = blockIdx.x * 256 + threadIdx.x;
    if (g < 16384)            Wpb[g] = f2bf(Wp[g]);
    else if (g < 49152)       Ws0b[g - 16384] = f2bf(Ws0[g - 16384]);
    else if (g < 81920)       Wn0b[g - 49152] = f2bf(Wn0[g - 49152]);
    else if (g < 344064)      Wihb[g - 81920] = f2bf(Wih[g - 81920]);
    else if (g < 606208)      Whhb[g - 344064] = f2bf(Whh[g - 344064]);
    else if (g < 607232) { const int i = g - 606208; bsum[i] = bih[i] + bhh[i]; }
}

// ---------------------------------------------------------------------------
// Stage A: pool-SAGE. Per block: 4 groups (60 gathered rows + 4 pad) x 128 cols,
// K=128 (2 staged chunks of 64). MFMA 16x16x32 bf16. relu+max epilogue via LDS
// atomicMax (uint-punned, vals >= 0). Output bf16.
// ---------------------------------------------------------------------------
__global__ __launch_bounds__(256) void pool_max_kernel(
    const float* __restrict__ x, const int* __restrict__ nbr0,
    const unsigned short* __restrict__ Wpb, const float* __restrict__ bp,
    unsigned short* __restrict__ hnb)
{
    __shared__ unsigned short smem[64 * 72 + 128 * 72];
    __shared__ unsigned red[512];
    __shared__ int nodes[64];
    unsigned short* aT = smem;
    unsigned short* wT = smem + 64 * 72;

    const int tid = threadIdx.x;
    const size_t base = (size_t)blockIdx.x * 60;
    if (tid < 64) nodes[tid] = (tid < 60) ? nbr0[base + tid] : 0;
    for (int i = tid; i < 512; i += 256) red[i] = 0u;

    const int lane = tid & 63, wv = tid >> 6;
    const int ml = lane & 15, q = lane >> 4, qk = q * 8;

    floatx4 acc[8];
#pragma unroll
    for (int ct = 0; ct < 8; ++ct) acc[ct] = (floatx4){0.f, 0.f, 0.f, 0.f};

    for (int kc = 0; kc < 2; ++kc) {
        __syncthreads();
        for (int i = tid; i < 512; i += 256) {            // A: 64 rows x 64 k
            const int row = i >> 3, seg = i & 7;
            short8 o = {0, 0, 0, 0, 0, 0, 0, 0};
            if (row < 60) {
                const float* s = x + (size_t)nodes[row] * 128 + kc * 64 + seg * 8;
                const float4 f0 = *(const float4*)s;
                const float4 f1 = *(const float4*)(s + 4);
                o[0] = (short)f2bf(flog1p(f0.x)); o[1] = (short)f2bf(flog1p(f0.y));
                o[2] = (short)f2bf(flog1p(f0.z)); o[3] = (short)f2bf(flog1p(f0.w));
                o[4] = (short)f2bf(flog1p(f1.x)); o[5] = (short)f2bf(flog1p(f1.y));
                o[6] = (short)f2bf(flog1p(f1.z)); o[7] = (short)f2bf(flog1p(f1.w));
            }
            *(short8*)&aT[row * 72 + seg * 8] = o;
        }
        for (int i = tid; i < 1024; i += 256) {           // W: 128 rows x 64 k
            const int row = i >> 3, seg = i & 7;
            *(short8*)&wT[row * 72 + seg * 8] =
                *(const short8*)&Wpb[(size_t)row * 128 + kc * 64 + seg * 8];
        }
        __syncthreads();
#pragma unroll
        for (int k0 = 0; k0 < 64; k0 += 32) {
            const short8 a = *(const short8*)&aT[(wv * 16 + ml) * 72 + k0 + qk];
#pragma unroll
            for (int ct = 0; ct < 8; ++ct) {
                const short8 b = *(const short8*)&wT[(ct * 16 + ml) * 72 + k0 + qk];
                acc[ct] = __builtin_amdgcn_mfma_f32_16x16x32_bf16(a, b, acc[ct], 0, 0, 0);
            }
        }
    }
    __syncthreads();
#pragma unroll
    for (int ct = 0; ct < 8; ++ct) {
        const int col = ct * 16 + ml;
        const float bb = bp[col];
#pragma unroll
        for (int r = 0; r < 4; ++r) {
            const int row = wv * 16 + q * 4 + r;
            if (row < 60) {
                const float v = fmaxf(acc[ct][r] + bb, 0.0f);
                atomicMax(&red[(row / 15) * 128 + col], __float_as_uint(v));
            }
        }
    }
    __syncthreads();
    for (int i = tid; i < 512; i += 256)
        hnb[(size_t)blockIdx.x * 512 + i] = f2bf(__uint_as_float(red[i]));
}

// ---------------------------------------------------------------------------
// Stage B: h0 = [log1p(x[:N1]) | h_neigh] @ [Ws0|Wn0]^T + b0, stored bf16 (pre-BN),
// with fused per-column sum/sumsq partials (LDS two-stage, 2 global atomics/col/blk).
// M=40960 (64/blk), N=256 (128/blk via gridDim.y=2), K=256 (4 chunks of 64).
// ---------------------------------------------------------------------------
__global__ __launch_bounds__(256) void h0_kernel(
    const float* __restrict__ x, const unsigned short* __restrict__ hnb,
    const unsigned short* __restrict__ Ws0b, const unsigned short* __restrict__ Wn0b,
    const float* __restrict__ b0, unsigned short* __restrict__ h0bf,
    float* __restrict__ bn_sum, float* __restrict__ bn_sq)
{
    __shared__ unsigned short smem[64 * 72 + 128 * 72];
    unsigned short* aT = smem;
    unsigned short* wT = smem + 64 * 72;

    const int tid = threadIdx.x;
    const int m0 = blockIdx.x * 64, c0 = blockIdx.y * 128;
    const int lane = tid & 63, wv = tid >> 6;
    const int ml = lane & 15, q = lane >> 4, qk = q * 8;

    floatx4 acc[8];
#pragma unroll
    for (int ct = 0; ct < 8; ++ct) acc[ct] = (floatx4){0.f, 0.f, 0.f, 0.f};

    for (int kc = 0; kc < 4; ++kc) {
        __syncthreads();
        for (int i = tid; i < 512; i += 256) {
            const int row = i >> 3, seg = i & 7;
            const int k = kc * 64 + seg * 8;
            if (kc < 2) {
                const float* s = x + (size_t)(m0 + row) * 128 + k;
                const float4 f0 = *(const float4*)s;
                const float4 f1 = *(const float4*)(s + 4);
                short8 o;
                o[0] = (short)f2bf(flog1p(f0.x)); o[1] = (short)f2bf(flog1p(f0.y));
                o[2] = (short)f2bf(flog1p(f0.z)); o[3] = (short)f2bf(flog1p(f0.w));
                o[4] = (short)f2bf(flog1p(f1.x)); o[5] = (short)f2bf(flog1p(f1.y));
                o[6] = (short)f2bf(flog1p(f1.z)); o[7] = (short)f2bf(flog1p(f1.w));
                *(short8*)&aT[row * 72 + seg * 8] = o;
            } else {
                *(short8*)&aT[row * 72 + seg * 8] =
                    *(const short8*)&hnb[(size_t)(m0 + row) * 128 + (k - 128)];
            }
        }
        for (int i = tid; i < 1024; i += 256) {
            const int row = i >> 3, seg = i & 7;
            const int k = kc * 64 + seg * 8;
            const size_t cg = (size_t)(c0 + row);
            *(short8*)&wT[row * 72 + seg * 8] = (kc < 2)
                ? *(const short8*)&Ws0b[cg * 128 + k]
                : *(const short8*)&Wn0b[cg * 128 + (k - 128)];
        }
        __syncthreads();
#pragma unroll
        for (int k0 = 0; k0 < 64; k0 += 32) {
            const short8 a = *(const short8*)&aT[(wv * 16 + ml) * 72 + k0 + qk];
#pragma unroll
            for (int ct = 0; ct < 8; ++ct) {
                const short8 b = *(const short8*)&wT[(ct * 16 + ml) * 72 + k0 + qk];
                acc[ct] = __builtin_amdgcn_mfma_f32_16x16x32_bf16(a, b, acc[ct], 0, 0, 0);
            }
        }
    }
    __syncthreads();
    float* scr = (float*)smem;   // 4096 floats = 16 KB <= 27.6 KB
#pragma unroll
    for (int ct = 0; ct < 8; ++ct) {
        const int col = ct * 16 + ml, cg = c0 + col;
        const float bb = b0[cg];
        float s = 0.f, sq = 0.f;
#pragma unroll
        for (int r = 0; r < 4; ++r) {
            const int row = wv * 16 + q * 4 + r;
            const float v = acc[ct][r] + bb;
            h0bf[(size_t)(m0 + row) * 256 + cg] = f2bf(v);
            s += v; sq += v * v;
        }
        scr[(wv * 4 + q) * 128 + col] = s;
        scr[2048 + (wv * 4 + q) * 128 + col] = sq;
    }
    __syncthreads();
    if (tid < 128) {
        float s = 0.f, sq = 0.f;
#pragma unroll
        for (int j = 0; j < 16; ++j) {
            s += scr[j * 128 + tid];
            sq += scr[2048 + j * 128 + tid];
        }
        atomicAdd(&bn_sum[c0 + tid], s);
        atomicAdd(&bn_sq[c0 + tid], sq);
    }
}

__global__ void bn_stats_kernel(const float* __restrict__ bn_sum, const float* __restrict__ bn_sq,
                                const float* __restrict__ gamma, const float* __restrict__ beta,
                                float* __restrict__ scale, float* __restrict__ shift)
{
    const int c = threadIdx.x;   // 256
    const float inv_n = 1.0f / (float)N1v;
    const float mu = bn_sum[c] * inv_n;
    const float var = bn_sq[c] * inv_n - mu * mu;
    const float rs = rsqrtf(var + 1e-5f);
    const float sc = rs * gamma[c];
    scale[c] = sc;
    shift[c] = beta[c] - mu * sc;
}

__global__ __launch_bounds__(256) void bn_apply_kernel(
    const unsigned short* __restrict__ h0bf, const float* __restrict__ scale,
    const float* __restrict__ shift, unsigned short* __restrict__ h0nbf)
{
    const int gid = blockIdx.x * 256 + threadIdx.x;   // over N1*256/8
    const int c0 = (gid * 8) & 255;
    const short8 v = *(const short8*)&h0bf[(size_t)gid * 8];
    short8 o;
#pragma unroll
    for (int j = 0; j < 8; ++j) {
        const float f = bf2f((unsigned short)v[j]);
        o[j] = (short)f2bf(fmaxf(fmaf(f, scale[c0 + j], shift[c0 + j]), 0.0f));
    }
    *(short8*)&h0nbf[(size_t)gid * 8] = o;
}

// ---------------------------------------------------------------------------
// Fused LSTM step: gates GEMM + pointwise in one kernel, no gbuf round-trip.
// Column tiling is gate-interleaved: each block computes a 32-wide h-slice for
// ALL FOUR gates (local col c in [0,128): gate = c>>5, hcol = c&31; W row =
// gate*256 + c0h + hcol).  Thread's acc[hg], acc[2+hg], acc[4+hg], acc[6+hg]
// are then (i,f,g,o) for one (row, hcol) -> LSTM pointwise in registers.
// K = [h0n[nbr1[:,t]] (256) | h_prev (256)]; at t=0 h_prev==0 so the Whh half
// of K is skipped entirely (and no hb0 memset is needed).
// M=4096 (64/blk), h-cols 256 (32/blk via gridDim.y=8).
// ---------------------------------------------------------------------------
__global__ __launch_bounds__(256) void lstm_step_kernel(
    const unsigned short* __restrict__ h0nbf, const int* __restrict__ nbr1,
    const unsigned short* __restrict__ hbprev, const unsigned short* __restrict__ Wihb,
    const unsigned short* __restrict__ Whhb, const float* __restrict__ bsum,
    float* __restrict__ cst, unsigned short* __restrict__ hb, int t)
{
    __shared__ unsigned short smem[64 * 72 + 128 * 72];
    __shared__ int nodes[64];
    unsigned short* aT = smem;
    unsigned short* wT = smem + 64 * 72;

    const int tid = threadIdx.x;
    const int m0 = blockIdx.x * 64, c0h = blockIdx.y * 32;
    const int lane = tid & 63, wv = tid >> 6;
    const int ml = lane & 15, q = lane >> 4, qk = q * 8;

    if (tid < 64) nodes[tid] = nbr1[(size_t)(m0 + tid) * 10 + t];

    floatx4 acc[8];
#pragma unroll
    for (int ct = 0; ct < 8; ++ct) acc[ct] = (floatx4){0.f, 0.f, 0.f, 0.f};

    const int kcN = (t == 0) ? 4 : 8;   // h_prev == 0 at t=0
    for (int kc = 0; kc < kcN; ++kc) {
        __syncthreads();
        for (int i = tid; i < 512; i += 256) {
            const int row = i >> 3, seg = i & 7;
            const int k = kc * 64 + seg * 8;
            *(short8*)&aT[row * 72 + seg * 8] = (kc < 4)
                ? *(const short8*)&h0nbf[(size_t)nodes[row] * 256 + k]
                : *(const short8*)&hbprev[(size_t)(m0 + row) * 256 + (k - 256)];
        }
        for (int i = tid; i < 1024; i += 256) {
            const int row = i >> 3, seg = i & 7;
            const int k = kc * 64 + seg * 8;
            // local W row -> gate-interleaved global row
            const size_t wr = (size_t)((row >> 5) * 256 + c0h + (row & 31));
            *(short8*)&wT[row * 72 + seg * 8] = (kc < 4)
                ? *(const short8*)&Wihb[wr * 256 + k]
                : *(const short8*)&Whhb[wr * 256 + (k - 256)];
        }
        __syncthreads();
#pragma unroll
        for (int k0 = 0; k0 < 64; k0 += 32) {
            const short8 a = *(const short8*)&aT[(wv * 16 + ml) * 72 + k0 + qk];
#pragma unroll
            for (int ct = 0; ct < 8; ++ct) {
                const short8 b = *(const short8*)&wT[(ct * 16 + ml) * 72 + k0 + qk];
                acc[ct] = __builtin_amdgcn_mfma_f32_16x16x32_bf16(a, b, acc[ct], 0, 0, 0);
            }
        }
    }
    // pointwise LSTM epilogue, fully in registers
#pragma unroll
    for (int hg = 0; hg < 2; ++hg) {
        const int hcol = hg * 16 + ml;
        const float bi = bsum[c0h + hcol];
        const float bf_ = bsum[256 + c0h + hcol];
        const float bg = bsum[512 + c0h + hcol];
        const float bo = bsum[768 + c0h + hcol];
#pragma unroll
        for (int r = 0; r < 4; ++r) {
            const int row = wv * 16 + q * 4 + r;
            const size_t idx = (size_t)(m0 + row) * 256 + c0h + hcol;
            const float gi = acc[hg][r] + bi;
            const float gf = acc[2 + hg][r] + bf_;
            const float gg = acc[4 + hg][r] + bg;
            const float go = acc[6 + hg][r] + bo;
            float c = sigf(gi) * tanhfast(gg);
            if (t > 0) c += sigf(gf) * cst[idx];
            cst[idx] = c;
            hb[idx] = f2bf(sigf(go) * tanhfast(c));
        }
    }
}

// Stage E: out = h0n[:B] @ W_self1^T + hT @ W_neigh1^T + b1   [4096 x 32]
__global__ __launch_bounds__(256) void out_kernel(
    const unsigned short* __restrict__ h0nbf, const unsigned short* __restrict__ hTb,
    const float* __restrict__ Ws1, const float* __restrict__ Wn1,
    const float* __restrict__ b1, float* __restrict__ out)
{
    const int gid = blockIdx.x * 256 + threadIdx.x;   // < 4096*32
    const int row = gid >> 5, c = gid & 31;
    const unsigned short* a0 = h0nbf + (size_t)row * 256;
    const unsigned short* a1 = hTb + (size_t)row * 256;
    const float* w0 = Ws1 + (size_t)c * 256;
    const float* w1 = Wn1 + (size_t)c * 256;
    float s = b1[c];
#pragma unroll 4
    for (int k8 = 0; k8 < 32; ++k8) {
        const short8 av = *(const short8*)&a0[k8 * 8];
        const short8 bv = *(const short8*)&a1[k8 * 8];
        const float4 wa0 = *(const float4*)&w0[k8 * 8];
        const float4 wa1 = *(const float4*)&w0[k8 * 8 + 4];
        const float4 wb0 = *(const float4*)&w1[k8 * 8];
        const float4 wb1 = *(const float4*)&w1[k8 * 8 + 4];
        s += bf2f((unsigned short)av[0]) * wa0.x + bf2f((unsigned short)av[1]) * wa0.y;
        s += bf2f((unsigned short)av[2]) * wa0.z + bf2f((unsigned short)av[3]) * wa0.w;
        s += bf2f((unsigned short)av[4]) * wa1.x + bf2f((unsigned short)av[5]) * wa1.y;
        s += bf2f((unsigned short)av[6]) * wa1.z + bf2f((unsigned short)av[7]) * wa1.w;
        s += bf2f((unsigned short)bv[0]) * wb0.x + bf2f((unsigned short)bv[1]) * wb0.y;
        s += bf2f((unsigned short)bv[2]) * wb0.z + bf2f((unsigned short)bv[3]) * wb0.w;
        s += bf2f((unsigned short)bv[4]) * wb1.x + bf2f((unsigned short)bv[5]) * wb1.y;
        s += bf2f((unsigned short)bv[6]) * wb1.z + bf2f((unsigned short)bv[7]) * wb1.w;
    }
    out[gid] = s;
}

extern "C" void kernel_launch(void* const* d_in, const int* in_sizes, int n_in,
                              void* d_out, int out_size, void* d_ws, size_t ws_size,
                              hipStream_t stream)
{
    const float* x        = (const float*)d_in[0];
    const int*   nbr0     = (const int*)d_in[1];
    const int*   nbr1     = (const int*)d_in[2];
    const float* W_pool   = (const float*)d_in[3];
    const float* b_pool   = (const float*)d_in[4];
    const float* W_self0  = (const float*)d_in[5];
    const float* W_neigh0 = (const float*)d_in[6];
    const float* b0       = (const float*)d_in[7];
    const float* gamma0   = (const float*)d_in[8];
    const float* beta0    = (const float*)d_in[9];
    const float* W_ih     = (const float*)d_in[10];
    const float* W_hh     = (const float*)d_in[11];
    const float* b_ih     = (const float*)d_in[12];
    const float* b_hh     = (const float*)d_in[13];
    const float* W_self1  = (const float*)d_in[14];
    const float* W_neigh1 = (const float*)d_in[15];
    const float* b1       = (const float*)d_in[16];
    float* out = (float*)d_out;

    // ws layout (bytes), fully disjoint. Total 62.04 MB (<= proven 75.5 MB).
    // gbuf is gone (LSTM pointwise fused into the gates epilogue).
    char* ws = (char*)d_ws;
    unsigned short* h0bf  = (unsigned short*)(ws);               // 20,971,520 B
    unsigned short* hnb   = (unsigned short*)(ws + 20971520);    // 10,485,760 B
    unsigned short* h0nbf = (unsigned short*)(ws + 31457280);    // 20,971,520 B
    float*          cst   = (float*)(ws + 52428800);             //  4,194,304 B
    unsigned short* hb0   = (unsigned short*)(ws + 56623104);    //  2,097,152 B
    unsigned short* hb1   = (unsigned short*)(ws + 58720256);    //  2,097,152 B
    unsigned short* Wpb   = (unsigned short*)(ws + 60817408);    //     32,768 B
    unsigned short* Ws0b  = (unsigned short*)(ws + 60850176);    //     65,536 B
    unsigned short* Wn0b  = (unsigned short*)(ws + 60915712);    //     65,536 B
    unsigned short* Wihb  = (unsigned short*)(ws + 60981248);    //    524,288 B
    unsigned short* Whhb  = (unsigned short*)(ws + 61505536);    //    524,288 B
    float*          bsum  = (float*)(ws + 62029824);             //      4,096 B
    float*          bn_sum   = (float*)(ws + 62033920);
    float*          bn_sq    = (float*)(ws + 62034944);
    float*          bn_scale = (float*)(ws + 62035968);
    float*          bn_shift = (float*)(ws + 62036992);

    hipMemsetAsync(bn_sum, 0, 2048, stream);        // bn_sum + bn_sq
    // NOTE: no hb0 memset needed anymore — t=0 skips the h_prev half of K.

    cvt_weights_kernel<<<2372, 256, 0, stream>>>(W_pool, W_self0, W_neigh0, W_ih, W_hh,
                                                 b_ih, b_hh, Wpb, Ws0b, Wn0b, Wihb, Whhb, bsum);
    pool_max_kernel<<<N1v / 4, 256, 0, stream>>>(x, nbr0, Wpb, b_pool, hnb);
    h0_kernel<<<dim3(N1v / 64, 2), 256, 0, stream>>>(x, hnb, Ws0b, Wn0b, b0,
                                                     h0bf, bn_sum, bn_sq);
    bn_stats_kernel<<<1, 256, 0, stream>>>(bn_sum, bn_sq, gamma0, beta0, bn_scale, bn_shift);
    bn_apply_kernel<<<(N1v * 256 / 8) / 256, 256, 0, stream>>>(h0bf, bn_scale, bn_shift, h0nbf);

    for (int t = 0; t < 10; ++t) {
        const unsigned short* hp = (t & 1) ? hb1 : hb0;
        unsigned short*       hn = (t & 1) ? hb0 : hb1;
        lstm_step_kernel<<<dim3(BATCHv / 64, 8), 256, 0, stream>>>(
            h0nbf, nbr1, hp, Wihb, Whhb, bsum, cst, hn, t);
    }
    // t=9 wrote hb0 -> final hidden state
    out_kernel<<<(BATCHv * 32) / 256, 256, 0, stream>>>(h0nbf, hb0, W_self1, W_neigh1, b1, out);
}